// Round 2
// baseline (411.817 us; speedup 1.0000x reference)
//
#include <hip/hip_runtime.h>

#define BATCH 262144
#define NH 64     // hidden width
#define NIN 64    // 2*D input width
#define ND 32     // q-dim (output width)

// ---------------------------------------------------------------------------
// Prep (re-runs every launch; d_ws is re-poisoned): fp32 W2 transpose and
// Mt[j][i] = W2[i][j] * w3[j].
// ---------------------------------------------------------------------------
__global__ void lnn_prep(const float* __restrict__ W2, const float* __restrict__ W3,
                         float* __restrict__ W2T, float* __restrict__ Mt) {
    int t = blockIdx.x * blockDim.x + threadIdx.x;
    if (t < NH * NH) {
        int i = t >> 6, j = t & 63;          // W2[i][j], row i contiguous
        float w = W2[t];
        W2T[j * NH + i] = w;                 // row j = column j of W2
        Mt[j * NH + i]  = w * W3[j];
    }
}

// ---------------------------------------------------------------------------
// One thread = one sample.
// MASK PATH (must be bit-exact with numpy/sgemm fp32):
//   z = ascending-k single-accumulator fused-FMA chain, then ONE add of bias.
//   This is exactly what OpenBLAS/MKL/Eigen sgemm + numpy's `+ b` produce.
// VALUE PATH (tolerance 2% of absmax): plain fp32.
// Weights are wave-uniform -> scalar loads; x/out per-lane.
// ---------------------------------------------------------------------------
__global__ __launch_bounds__(256) void lnn_main(
        const float* __restrict__ X,
        const float* __restrict__ W1,  const float* __restrict__ b1,
        const float* __restrict__ W2T, const float* __restrict__ b2,
        const float* __restrict__ Mt,
        float* __restrict__ out) {
    const int s = blockIdx.x * blockDim.x + threadIdx.x;
    const float* __restrict__ xp = X + (size_t)s * NIN;

    // ---- phase A: dot part of z1 = x @ W1 (64 independent ascending-i chains)
    float acc[NH];
#pragma unroll
    for (int j = 0; j < NH; ++j) acc[j] = 0.0f;

    for (int ig = 0; ig < NIN / 4; ++ig) {            // float4 x loads
        const float4 xv = reinterpret_cast<const float4*>(xp)[ig];
        const float xs[4] = {xv.x, xv.y, xv.z, xv.w};
#pragma unroll
        for (int ii = 0; ii < 4; ++ii) {
            const float* __restrict__ wr = W1 + (ig * 4 + ii) * NH;  // uniform -> s_load
#pragma unroll
            for (int j = 0; j < NH; ++j)
                acc[j] = fmaf(xs[ii], wr[j], acc[j]); // ascending i, single acc per j
        }
    }

    // z1 = acc + b1 (one rounded add, AFTER the chain, like numpy), relu, mask
    unsigned long long r1 = 0ull;
    float h[NH];
#pragma unroll
    for (int j = 0; j < NH; ++j) {
        const float z1 = acc[j] + b1[j];
        if (z1 > 0.0f) r1 |= (1ull << j);
        h[j] = fmaxf(z1, 0.0f);
    }

    // ---- phase B1: z2_j = (h @ W2[:,j]) + b2_j, fp32 chains; keep sign bits.
    // 4 j's at a time = 4 independent chains for ILP; each chain ascending i.
    unsigned long long r2 = 0ull;
    for (int jg = 0; jg < NH / 4; ++jg) {
        float p0 = 0.f, p1 = 0.f, p2 = 0.f, p3 = 0.f;
        const float* __restrict__ w0 = W2T + (jg * 4 + 0) * NH;
        const float* __restrict__ w1 = W2T + (jg * 4 + 1) * NH;
        const float* __restrict__ w2 = W2T + (jg * 4 + 2) * NH;
        const float* __restrict__ w3 = W2T + (jg * 4 + 3) * NH;
#pragma unroll
        for (int i = 0; i < NH; ++i) {
            p0 = fmaf(h[i], w0[i], p0);
            p1 = fmaf(h[i], w1[i], p1);
            p2 = fmaf(h[i], w2[i], p2);
            p3 = fmaf(h[i], w3[i], p3);
        }
        if (p0 + b2[jg * 4 + 0] > 0.0f) r2 |= (1ull << (jg * 4 + 0));
        if (p1 + b2[jg * 4 + 1] > 0.0f) r2 |= (1ull << (jg * 4 + 1));
        if (p2 + b2[jg * 4 + 2] > 0.0f) r2 |= (1ull << (jg * 4 + 2));
        if (p3 + b2[jg * 4 + 3] > 0.0f) r2 |= (1ull << (jg * 4 + 3));
    }
    // h dead from here -> register pressure drops.

    // ---- phase B2 (values): t_i = sum_{j: r2_j} W2[i,j]*w3_j = sum_j m2_j*Mt[j][i]
    float t_[NH];
#pragma unroll
    for (int i = 0; i < NH; ++i) t_[i] = 0.0f;

    for (int j = 0; j < NH; ++j) {
        const float m = ((r2 >> j) & 1ull) ? 1.0f : 0.0f;
        const float* __restrict__ mr = Mt + j * NH;   // uniform -> s_load
#pragma unroll
        for (int i = 0; i < NH; ++i) t_[i] = fmaf(m, mr[i], t_[i]);
    }

    // u = r1 .* t
#pragma unroll
    for (int i = 0; i < NH; ++i)
        t_[i] = ((r1 >> i) & 1ull) ? t_[i] : 0.0f;

    // ---- phase C (values): out_k = -W1[k,:] . u, k = 0..31; float4 stores
    float* __restrict__ op = out + (size_t)s * ND;
    for (int kq = 0; kq < ND / 4; ++kq) {
        float a[4];
#pragma unroll
        for (int kk = 0; kk < 4; ++kk) {
            const float* __restrict__ wr = W1 + (kq * 4 + kk) * NIN;  // W1 row k
            float q0 = 0.f, q1 = 0.f;
#pragma unroll
            for (int i = 0; i < NH; i += 2) {
                q0 = fmaf(wr[i],     t_[i],     q0);
                q1 = fmaf(wr[i + 1], t_[i + 1], q1);
            }
            a[kk] = -(q0 + q1);
        }
        float4 ov;
        ov.x = a[0]; ov.y = a[1]; ov.z = a[2]; ov.w = a[3];
        reinterpret_cast<float4*>(op)[kq] = ov;
    }
}

extern "C" void kernel_launch(void* const* d_in, const int* in_sizes, int n_in,
                              void* d_out, int out_size, void* d_ws, size_t ws_size,
                              hipStream_t stream) {
    const float* X  = (const float*)d_in[0];
    const float* W1 = (const float*)d_in[1];
    const float* b1 = (const float*)d_in[2];
    const float* W2 = (const float*)d_in[3];
    const float* b2 = (const float*)d_in[4];
    const float* W3 = (const float*)d_in[5];
    // d_in[6] = b3: does not affect gradients.
    float* out = (float*)d_out;

    char* ws = (char*)d_ws;
    float* W2T = (float*)(ws);            // 16384 B
    float* Mt  = (float*)(ws + 16384);    // 16384 B

    lnn_prep<<<16, 256, 0, stream>>>(W2, W3, W2T, Mt);
    lnn_main<<<BATCH / 256, 256, 0, stream>>>(X, W1, b1, W2T, b2, Mt, out);
}